// Round 4
// baseline (414.937 us; speedup 1.0000x reference)
//
#include <hip/hip_runtime.h>
#include <hip/hip_fp16.h>

#define C 4096
#define NN 110
#define MPAD 112
#define BN 256        // n-cols per block tile: 1KB fp32 per row-chunk
#define BK 32         // k-rows per stage = one MFMA k-step
#define ASTR 40       // As row stride in halfs (32 + 8 pad -> conflict-free b128)

typedef _Float16 f16x8 __attribute__((ext_vector_type(8)));
typedef _Float16 f16x4 __attribute__((ext_vector_type(4)));
typedef float fx4 __attribute__((ext_vector_type(4)));

#define AS_GLB __attribute__((address_space(1)))
#define AS_LDS __attribute__((address_space(3)))

// ---------------------------------------------------------------------------
// prep1: A1[112][4096] = fp16(x), rows >=110 zeroed
// ---------------------------------------------------------------------------
__global__ void prep1_kernel(const float* __restrict__ x, _Float16* __restrict__ A1) {
    int idx = blockIdx.x * 256 + threadIdx.x;
    int n = idx >> 12;
    float v = (n < NN) ? x[idx] : 0.f;
    A1[idx] = (_Float16)v;
}

// ---------------------------------------------------------------------------
// mm: Cacc[0:110, n0:n0+256] += A16[:, k0:k0+kch] @ fp16(B[k0:k0+kch, n0:n0+256])
// Staging designed around the r1-r3 finding that small strided HBM chunks cap
// at ~1 TB/s: each global_load_lds instruction covers ONE contiguous 1KB
// row-chunk (64 lanes x 16B, row = w*8+j, lanes sweep all 256 cols).
// A k-slice (112x32 fp16, L2-resident) is staged into padded LDS via b64 +
// ds_write so inner-loop A reads are conflict-free ds_read_b128, never global.
// Single-buffered 41.7KB LDS -> 2 blocks/CU; cross-block overlap hides the
// stage drain. 4 waves; wave w owns cols w*64..w*64+63 (4 n-frags).
// fp32 atomicAdd epilogue (Cacc pre-zeroed).
// ---------------------------------------------------------------------------
__global__ __launch_bounds__(256, 2)
void mm_kernel(const _Float16* __restrict__ A, const float* __restrict__ B,
               float* __restrict__ Cacc, int lda, int kch) {
    __shared__ float    Bs[BK * BN];       // 32 KB, [k][n] raw fp32
    __shared__ _Float16 As[MPAD * ASTR];   // 8.75 KB, padded

    const int t   = threadIdx.x;
    const int w   = t >> 6;
    const int L   = t & 63;
    const int l15 = L & 15;
    const int q   = L >> 4;                       // quad 0..3
    const int n0  = blockIdx.x * BN;
    const int k0  = blockIdx.y * kch;

    fx4 acc[7][4];
    #pragma unroll
    for (int mt = 0; mt < 7; ++mt)
        #pragma unroll
        for (int nt = 0; nt < 4; ++nt)
            acc[mt][nt] = (fx4){0.f, 0.f, 0.f, 0.f};

    #pragma unroll 1
    for (int kc = 0; kc < kch; kc += BK) {
        // ---- stage B: 32 rows x 1KB, one contiguous row-chunk per instruction
        #pragma unroll
        for (int j = 0; j < 8; ++j) {
            const int row = w * 8 + j;                         // 0..31
            const float* g = B + (size_t)(k0 + kc + row) * C + n0 + L * 4;
            __builtin_amdgcn_global_load_lds((const AS_GLB void*)g,
                                             (AS_LDS void*)(Bs + row * BN), 16, 0, 0);
        }
        // ---- stage A: 112 rows x 32 halfs (64B/row) via b64 -> padded LDS
        #pragma unroll
        for (int i = 0; i < 4; ++i) {
            int idx = t + i * 256;
            if (idx < MPAD * 8) {                              // 896 b64-chunks
                int row = idx >> 3;
                int c4  = (idx & 7) * 4;
                f16x4 v = *(const f16x4*)(A + (size_t)row * lda + k0 + kc + c4);
                *(f16x4*)(As + row * ASTR + c4) = v;
            }
        }
        __syncthreads();                                       // drain vmcnt+lds
        // ---- one MFMA k-step: 4 bfrags (LDS cols + cvt), 7 afrags (b128), 28 MFMA
        f16x8 bfrag[4];
        #pragma unroll
        for (int nt = 0; nt < 4; ++nt)
            #pragma unroll
            for (int j = 0; j < 8; ++j)
                bfrag[nt][j] = (_Float16)Bs[(q * 8 + j) * BN + w * 64 + nt * 16 + l15];
        #pragma unroll
        for (int mt = 0; mt < 7; ++mt) {
            f16x8 af = *(const f16x8*)(As + (mt * 16 + l15) * ASTR + q * 8);
            #pragma unroll
            for (int nt = 0; nt < 4; ++nt)
                acc[mt][nt] = __builtin_amdgcn_mfma_f32_16x16x32_f16(af, bfrag[nt],
                                                                     acc[mt][nt], 0, 0, 0);
        }
        __syncthreads();                                       // protect Bs/As reuse
    }

    // ---- epilogue (C/D layout: col=lane&15, row=q*4+reg)
    #pragma unroll
    for (int mt = 0; mt < 7; ++mt) {
        #pragma unroll
        for (int nt = 0; nt < 4; ++nt) {
            const int col = n0 + w * 64 + nt * 16 + l15;
            #pragma unroll
            for (int r = 0; r < 4; ++r) {
                int row = mt * 16 + q * 4 + r;
                if (row < NN)
                    atomicAdd(&Cacc[(size_t)row * C + col], acc[mt][nt][r]);
            }
        }
    }
}

// ---------------------------------------------------------------------------
// agg: per 16-col tile, builds A3 = fp16([h+b2, aggr]) [112][8192]
// ---------------------------------------------------------------------------
__global__ __launch_bounds__(256)
void agg_kernel(const float* __restrict__ h_raw, const int* __restrict__ adj,
                const float* __restrict__ b2, _Float16* __restrict__ A3) {
    __shared__ float hb[NN * 16];
    __shared__ unsigned long long mlo[NN], mhi[NN];
    __shared__ float degs[NN];
    const int t  = threadIdx.x;
    const int c0 = blockIdx.x * 16;

    for (int idx = t; idx < NN * 16; idx += 256) {
        int n = idx >> 4, c = idx & 15;
        float v = h_raw[(size_t)n * C + c0 + c] + b2[c0 + c];
        hb[idx] = v;
        A3[(size_t)n * (2 * C) + c0 + c] = (_Float16)v;
    }
    if (t < 64) {
        int n  = NN + (t >> 5);
        int hs = (t >> 4) & 1;
        int c  = t & 15;
        A3[(size_t)n * (2 * C) + hs * C + c0 + c] = (_Float16)0.f;
    }
    if (t < NN) {
        int j = t;
        unsigned long long lo = 0, hi = 0;
        int dg = 0;
        for (int i = 0; i < 64; ++i) {
            int m = (adj[i * NN + j] != 0);
            lo |= ((unsigned long long)m) << i; dg += m;
        }
        for (int i = 64; i < NN; ++i) {
            int m = (adj[i * NN + j] != 0);
            hi |= ((unsigned long long)m) << (i - 64); dg += m;
        }
        mlo[j] = lo; mhi[j] = hi;
        degs[j] = (float)(dg > 0 ? dg : 1);
    }
    __syncthreads();
    for (int idx = t; idx < NN * 16; idx += 256) {
        int j = idx >> 4, c = idx & 15;
        unsigned long long lo = mlo[j], hi = mhi[j];
        float a = 0.f;
        #pragma unroll 2
        for (int i = 0; i < 64; ++i)
            a = fmaf((float)((lo >> i) & 1ull), hb[i * 16 + c], a);
        #pragma unroll 2
        for (int i = 64; i < NN; ++i)
            a = fmaf((float)((hi >> (i - 64)) & 1ull), hb[i * 16 + c], a);
        A3[(size_t)j * (2 * C) + C + c0 + c] = (_Float16)(a / degs[j]);
    }
}

// ---------------------------------------------------------------------------
// fin: out[j,c] = sum_k Wl[j,k] * relu(z_raw[k,c]+b1[c]) + bl[j]
// ---------------------------------------------------------------------------
__global__ __launch_bounds__(256)
void fin_kernel(const float* __restrict__ z_raw, const float* __restrict__ b1,
                const float* __restrict__ Wl, const float* __restrict__ bl,
                float* __restrict__ out) {
    __shared__ float zs[NN * 64];
    const int t  = threadIdx.x;
    const int c0 = blockIdx.x * 64;
    const int j  = blockIdx.y * 4 + (t >> 6);
    const int c  = t & 63;

    for (int idx = t; idx < NN * 64; idx += 256) {
        int k = idx >> 6, cc = idx & 63;
        float v = z_raw[(size_t)k * C + c0 + cc] + b1[c0 + cc];
        zs[idx] = fmaxf(v, 0.f);
    }
    __syncthreads();
    if (j < NN) {
        float a = bl[j];
        #pragma unroll 2
        for (int k = 0; k < NN; ++k)
            a += Wl[j * NN + k] * zs[k * 64 + c];
        out[(size_t)j * C + c0 + c] = a;
    }
}

// ---------------------------------------------------------------------------
extern "C" void kernel_launch(void* const* d_in, const int* in_sizes, int n_in,
                              void* d_out, int out_size, void* d_ws, size_t ws_size,
                              hipStream_t stream) {
    const float* x   = (const float*)d_in[0];
    const int*   adj = (const int*)d_in[1];
    const float* W2  = (const float*)d_in[2];
    const float* b2  = (const float*)d_in[3];
    const float* W1  = (const float*)d_in[4];
    const float* b1  = (const float*)d_in[5];
    const float* Wl  = (const float*)d_in[6];
    const float* bl  = (const float*)d_in[7];
    float* out = (float*)d_out;

    char* ws = (char*)d_ws;
    float*    h_raw = (float*)(ws);                    // 110*4096 f32
    float*    z_raw = (float*)(ws + 1802240);          // 110*4096 f32
    _Float16* A1    = (_Float16*)(ws + 3604480);       // 112*4096 f16
    _Float16* A3    = (_Float16*)(ws + 4521984);       // 112*8192 f16

    hipMemsetAsync(d_ws, 0, 3604480, stream);          // zero h_raw, z_raw
    prep1_kernel<<<(MPAD * C) / 256, 256, 0, stream>>>(x, A1);
    // mm1: K=4096, kch=128 -> grid (16 ntiles, 32 chunks) = 512 blocks
    mm_kernel<<<dim3(C / BN, 32), 256, 0, stream>>>(A1, W2, h_raw, C, 128);
    agg_kernel<<<C / 16, 256, 0, stream>>>(h_raw, adj, b2, A3);
    // mm2: K=8192, kch=256 -> grid (16, 32) = 512 blocks
    mm_kernel<<<dim3(C / BN, 32), 256, 0, stream>>>(A3, W1, z_raw, 2 * C, 256);
    fin_kernel<<<dim3(C / 64, 28), 256, 0, stream>>>(z_raw, b1, Wl, bl, out);
}

// Round 5
// 396.367 us; speedup vs baseline: 1.0469x; 1.0469x over previous
//
#include <hip/hip_runtime.h>
#include <hip/hip_fp16.h>

#define C 4096
#define NN 110
#define MPAD 112

typedef _Float16 f16x8 __attribute__((ext_vector_type(8)));
typedef _Float16 f16x4 __attribute__((ext_vector_type(4)));
typedef float fx4 __attribute__((ext_vector_type(4)));

#define AS_GLB __attribute__((address_space(1)))
#define AS_LDS __attribute__((address_space(3)))

// ---------------------------------------------------------------------------
// repack: W fp32 [K][4096] -> B16 fp16 mini-tiled:
//   half_index(nt,kt,c,kk) = ((nt*(K/32) + kt)*128 + c)*32 + kk
//   nt = col/128 (32 tiles), kt = k/32, c = col%128, kk = k%32.
// One (nt,kt) region = 8KB contiguous = exactly one GEMM stage, k-contiguous
// per column -> GEMM B-frags are ds_read_b128. Block (kt, cs): rows kt*32..+31,
// cols cs*1024..+1023. Reads: 4KB contiguous bursts (vs r4's 1KB @16KB stride);
// writes: 1KB contiguous per wave-instr. LDS transpose Ls[1024][36] (72KB,
// stride 36 halves: 8B-aligned for b64, x18 bank swizzle -> conflict-light).
// ---------------------------------------------------------------------------
__global__ __launch_bounds__(256, 2)
void repack_kernel(const float* __restrict__ W, _Float16* __restrict__ B16, int K) {
    __shared__ _Float16 Ls[1024 * 36];
    const int t  = threadIdx.x;
    const int kt = blockIdx.x;
    const int cs = blockIdx.y;
    const int Kt = K >> 5;

    const float* src = W + (size_t)(kt * 32) * C + cs * 1024;
    #pragma unroll 4
    for (int i = 0; i < 32; ++i) {
        int idx = t + i * 256;              // 0..8191
        int r   = idx >> 8;                 // row 0..31
        int c4  = (idx & 255) * 4;          // col 0..1020
        fx4 v = *(const fx4*)(src + (size_t)r * C + c4);
        #pragma unroll
        for (int j = 0; j < 4; ++j)
            Ls[(c4 + j) * 36 + r] = (_Float16)v[j];
    }
    __syncthreads();
    #pragma unroll 4
    for (int i = 0; i < 16; ++i) {
        int o   = t + i * 256;              // 0..4095
        int kk8 = (o & 3) * 8;
        int c   = (o >> 2) & 127;
        int nt8 = o >> 9;                   // 0..7
        const _Float16* lp = Ls + (nt8 * 128 + c) * 36 + kk8;
        f16x4 a = *(const f16x4*)(lp);
        f16x4 b = *(const f16x4*)(lp + 4);
        f16x8 vv;
        vv[0]=a[0]; vv[1]=a[1]; vv[2]=a[2]; vv[3]=a[3];
        vv[4]=b[0]; vv[5]=b[1]; vv[6]=b[2]; vv[7]=b[3];
        _Float16* dst = B16 + (((size_t)(cs * 8 + nt8) * Kt + kt) * 128 + c) * 32 + kk8;
        *(f16x8*)dst = vv;                  // consecutive lanes -> contiguous 1KB
    }
}

// ---------------------------------------------------------------------------
// prep1: A1[112][4096] = fp16(x), rows >=110 zeroed
// ---------------------------------------------------------------------------
__global__ void prep1_kernel(const float* __restrict__ x, _Float16* __restrict__ A1) {
    int idx = blockIdx.x * 256 + threadIdx.x;
    int n = idx >> 12;
    float v = (n < NN) ? x[idx] : 0.f;
    A1[idx] = (_Float16)v;
}

// ---------------------------------------------------------------------------
// mm: pc[kc][nt][110][128] = A16[0:112, kc-chunk] @ B16-minitile(nt, kc-chunk)
// Block (nt,kc), 4 waves; wave w cols w*32..+31 (2 n-frags); 7 m-tiles; acc 7x2.
// B stage = ONE 8KB contiguous mini-tile via 8x global_load_lds (16B/lane),
// A stage = 112x32 fp16 b64->padded LDS. Double-buffered, 1 barrier/stage.
// Epilogue: plain coalesced stores into a private contiguous slab (NO atomics).
// ---------------------------------------------------------------------------
__global__ __launch_bounds__(256, 2)
void mm_kernel(const _Float16* __restrict__ A, const _Float16* __restrict__ B16,
               float* __restrict__ pc, int lda, int kch) {
    __shared__ _Float16 Bs[2][32 * 128];     // 8KB each
    __shared__ _Float16 As[2][MPAD * 40];    // 8.96KB each, pad 40
    const int t   = threadIdx.x;
    const int w   = t >> 6;
    const int L   = t & 63;
    const int l15 = L & 15;
    const int q   = L >> 4;
    const int nt  = blockIdx.x;              // 0..31
    const int kc  = blockIdx.y;              // 0..15
    const int Kt  = lda >> 5;
    const int kt0 = (kc * kch) >> 5;
    const int stages = kch >> 5;

    const _Float16* Bbase = B16 + ((size_t)nt * Kt + kt0) * 4096;

    auto stageB = [&](int buf, int s) {
        const _Float16* g = Bbase + (size_t)s * 4096 + (2 * w) * 512 + L * 8;
        _Float16* l = &Bs[buf][(2 * w) * 512];
        __builtin_amdgcn_global_load_lds((const AS_GLB void*)g, (AS_LDS void*)l, 16, 0, 0);
        __builtin_amdgcn_global_load_lds((const AS_GLB void*)(g + 512),
                                         (AS_LDS void*)(l + 512), 16, 0, 0);
    };
    auto stageA = [&](int buf, int s) {
        int k0 = kc * kch + s * 32;
        #pragma unroll
        for (int i = 0; i < 4; ++i) {
            int idx = t + i * 256;
            if (idx < MPAD * 8) {
                int row = idx >> 3, c4 = (idx & 7) * 4;
                f16x4 v = *(const f16x4*)(A + (size_t)row * lda + k0 + c4);
                *(f16x4*)(&As[buf][row * 40 + c4]) = v;
            }
        }
    };

    fx4 acc[7][2];
    #pragma unroll
    for (int mt = 0; mt < 7; ++mt)
        #pragma unroll
        for (int n2 = 0; n2 < 2; ++n2)
            acc[mt][n2] = (fx4){0.f, 0.f, 0.f, 0.f};

    stageB(0, 0); stageA(0, 0);
    #pragma unroll 1
    for (int s = 0; s < stages; ++s) {
        int buf = s & 1;
        __syncthreads();                         // drains this wave's vm+lds ops
        if (s + 1 < stages) { stageB(buf ^ 1, s + 1); stageA(buf ^ 1, s + 1); }
        f16x8 bfrag[2];
        #pragma unroll
        for (int n2 = 0; n2 < 2; ++n2) {
            int cc = w * 32 + n2 * 16 + l15;
            bfrag[n2] = *(const f16x8*)(&Bs[buf][cc * 32 + q * 8]);   // b128, k-contig
        }
        #pragma unroll
        for (int mt = 0; mt < 7; ++mt) {
            f16x8 af = *(const f16x8*)(&As[buf][(mt * 16 + l15) * 40 + q * 8]);
            #pragma unroll
            for (int n2 = 0; n2 < 2; ++n2)
                acc[mt][n2] = __builtin_amdgcn_mfma_f32_16x16x32_f16(af, bfrag[n2],
                                                                     acc[mt][n2], 0, 0, 0);
        }
    }

    // epilogue: private slab, coalesced stores (C/D: col=lane&15, row=q*4+reg)
    float* base = pc + (size_t)(kc * 32 + nt) * NN * 128;
    #pragma unroll
    for (int mt = 0; mt < 7; ++mt)
        #pragma unroll
        for (int n2 = 0; n2 < 2; ++n2) {
            int col = w * 32 + n2 * 16 + l15;
            #pragma unroll
            for (int r = 0; r < 4; ++r) {
                int row = mt * 16 + q * 4 + r;
                if (row < NN) base[(size_t)row * 128 + col] = acc[mt][n2][r];
            }
        }
}

// ---------------------------------------------------------------------------
// agg: per 16-col tile: h = sum(pc1 slabs)+b2; emits A3 = fp16([h, aggr])
// ---------------------------------------------------------------------------
__global__ __launch_bounds__(256)
void agg_kernel(const float* __restrict__ pc1, const int* __restrict__ adj,
                const float* __restrict__ b2, _Float16* __restrict__ A3) {
    __shared__ float hb[NN * 16];
    __shared__ unsigned long long mlo[NN], mhi[NN];
    __shared__ float degs[NN];
    const int t  = threadIdx.x;
    const int c0 = blockIdx.x * 16;
    const int nt = c0 >> 7;

    for (int idx = t; idx < NN * 16; idx += 256) {
        int n = idx >> 4, c = idx & 15;
        int cg = c0 + c, cl = cg & 127;
        float v = b2[cg];
        #pragma unroll 4
        for (int kc = 0; kc < 16; ++kc)
            v += pc1[((size_t)(kc * 32 + nt) * NN + n) * 128 + cl];
        hb[idx] = v;
        A3[(size_t)n * (2 * C) + cg] = (_Float16)v;
    }
    if (t < 64) {
        int n  = NN + (t >> 5);
        int hs = (t >> 4) & 1;
        int c  = t & 15;
        A3[(size_t)n * (2 * C) + hs * C + c0 + c] = (_Float16)0.f;
    }
    if (t < NN) {
        int j = t;
        unsigned long long lo = 0, hi = 0;
        int dg = 0;
        for (int i = 0; i < 64; ++i) {
            int m = (adj[i * NN + j] != 0);
            lo |= ((unsigned long long)m) << i; dg += m;
        }
        for (int i = 64; i < NN; ++i) {
            int m = (adj[i * NN + j] != 0);
            hi |= ((unsigned long long)m) << (i - 64); dg += m;
        }
        mlo[j] = lo; mhi[j] = hi;
        degs[j] = (float)(dg > 0 ? dg : 1);
    }
    __syncthreads();
    for (int idx = t; idx < NN * 16; idx += 256) {
        int j = idx >> 4, c = idx & 15;
        unsigned long long lo = mlo[j], hi = mhi[j];
        float a = 0.f;
        #pragma unroll 2
        for (int i = 0; i < 64; ++i)
            a = fmaf((float)((lo >> i) & 1ull), hb[i * 16 + c], a);
        #pragma unroll 2
        for (int i = 64; i < NN; ++i)
            a = fmaf((float)((hi >> (i - 64)) & 1ull), hb[i * 16 + c], a);
        A3[(size_t)j * (2 * C) + C + c0 + c] = (_Float16)(a / degs[j]);
    }
}

// ---------------------------------------------------------------------------
// zred: z[110][4096] = relu(b1 + sum over 16 pc2 slabs)
// ---------------------------------------------------------------------------
__global__ __launch_bounds__(256)
void zred_kernel(const float* __restrict__ pc2, const float* __restrict__ b1,
                 float* __restrict__ z) {
    int idx = blockIdx.x * 256 + threadIdx.x;     // 110*4096
    int n = idx >> 12;
    int c = idx & 4095;
    int nt = c >> 7, cl = c & 127;
    float v = b1[c];
    #pragma unroll 4
    for (int kc = 0; kc < 16; ++kc)
        v += pc2[((size_t)(kc * 32 + nt) * NN + n) * 128 + cl];
    z[idx] = fmaxf(v, 0.f);
}

// ---------------------------------------------------------------------------
// fin: out[j,c] = sum_k Wl[j,k] * z[k,c] + bl[j]   (z already relu'd)
// ---------------------------------------------------------------------------
__global__ __launch_bounds__(256)
void fin_kernel(const float* __restrict__ z, const float* __restrict__ Wl,
                const float* __restrict__ bl, float* __restrict__ out) {
    __shared__ float zs[NN * 64];
    const int t  = threadIdx.x;
    const int c0 = blockIdx.x * 64;
    const int j  = blockIdx.y * 4 + (t >> 6);
    const int c  = t & 63;

    for (int idx = t; idx < NN * 64; idx += 256) {
        int k = idx >> 6, cc = idx & 63;
        zs[idx] = z[(size_t)k * C + c0 + cc];
    }
    __syncthreads();
    if (j < NN) {
        float a = bl[j];
        #pragma unroll 2
        for (int k = 0; k < NN; ++k)
            a += Wl[j * NN + k] * zs[k * 64 + c];
        out[(size_t)j * C + c0 + c] = a;
    }
}

// ---------------------------------------------------------------------------
extern "C" void kernel_launch(void* const* d_in, const int* in_sizes, int n_in,
                              void* d_out, int out_size, void* d_ws, size_t ws_size,
                              hipStream_t stream) {
    const float* x   = (const float*)d_in[0];
    const int*   adj = (const int*)d_in[1];
    const float* W2  = (const float*)d_in[2];
    const float* b2  = (const float*)d_in[3];
    const float* W1  = (const float*)d_in[4];
    const float* b1  = (const float*)d_in[5];
    const float* Wl  = (const float*)d_in[6];
    const float* bl  = (const float*)d_in[7];
    float* out = (float*)d_out;

    char* ws = (char*)d_ws;
    _Float16* B16a = (_Float16*)(ws);                       // 33,554,432 B
    _Float16* B16b = (_Float16*)(ws + 33554432);            // 67,108,864 B
    float*    pc1  = (float*)(ws + 100663296);              // 28,835,840 B
    float*    pc2  = (float*)(ws + 129499136);              // 28,835,840 B
    float*    z    = (float*)(ws + 158334976);              //  1,802,240 B
    _Float16* A1   = (_Float16*)(ws + 160137216);           //    917,504 B
    _Float16* A3   = (_Float16*)(ws + 161054720);           //  1,835,008 B

    repack_kernel<<<dim3(128, 4), 256, 0, stream>>>(W2, B16a, 4096);
    repack_kernel<<<dim3(256, 4), 256, 0, stream>>>(W1, B16b, 8192);
    prep1_kernel<<<(MPAD * C) / 256, 256, 0, stream>>>(x, A1);
    mm_kernel<<<dim3(32, 16), 256, 0, stream>>>(A1, B16a, pc1, 4096, 256);
    agg_kernel<<<C / 16, 256, 0, stream>>>(pc1, adj, b2, A3);
    mm_kernel<<<dim3(32, 16), 256, 0, stream>>>(A3, B16b, pc2, 8192, 512);
    zred_kernel<<<(NN * C) / 256, 256, 0, stream>>>(pc2, b1, z);
    fin_kernel<<<dim3(C / 64, 28), 256, 0, stream>>>(z, Wl, bl, out);
}